// Round 1
// baseline (271.053 us; speedup 1.0000x reference)
//
#include <hip/hip_runtime.h>

// out[i, 0:48]  = x[i, :]
// out[i, 48:96] = sum over edges e with row[e]==i of x[col[e], :]
// x: [N, 48] f32, edge_index: [2, E] int (row = ei[0:E], col = ei[E:2E])
// out: [N, 96] f32

constexpr int D_IN  = 48;
constexpr int D_OUT = 96;

// One thread per float4 of the output. 24 float4 per node:
// q in [0,12) -> copy from x; q in [12,24) -> zero (accumulator init).
__global__ void init_out_kernel(const float4* __restrict__ x4,
                                float4* __restrict__ out4,
                                int n_nodes) {
    int idx = blockIdx.x * blockDim.x + threadIdx.x;
    int total = n_nodes * 24;
    if (idx >= total) return;
    int i = idx / 24;
    int q = idx - i * 24;
    float4 v;
    if (q < 12) {
        v = x4[i * 12 + q];
    } else {
        v = make_float4(0.f, 0.f, 0.f, 0.f);
    }
    out4[idx] = v;
}

// One thread per (edge, dim). 48 consecutive threads share one edge, so the
// x[col] gather is coalesced within a 192B row and the row/col index loads
// broadcast from L1.
__global__ void scatter_add_kernel(const float* __restrict__ x,
                                   const int* __restrict__ row,
                                   const int* __restrict__ col,
                                   float* __restrict__ out,
                                   int n_edges) {
    long long gid = (long long)blockIdx.x * blockDim.x + threadIdx.x;
    long long total = (long long)n_edges * D_IN;
    if (gid >= total) return;
    int e = (int)(gid / D_IN);
    int d = (int)(gid - (long long)e * D_IN);
    int r = row[e];
    int c = col[e];
    atomicAdd(out + (long long)r * D_OUT + D_IN + d,
              x[(long long)c * D_IN + d]);
}

extern "C" void kernel_launch(void* const* d_in, const int* in_sizes, int n_in,
                              void* d_out, int out_size, void* d_ws, size_t ws_size,
                              hipStream_t stream) {
    const float* x  = (const float*)d_in[0];
    const int*   ei = (const int*)d_in[1];
    float*       out = (float*)d_out;

    int n_nodes = in_sizes[0] / D_IN;   // 100000
    int n_edges = in_sizes[1] / 2;      // 1600000
    const int* row = ei;
    const int* col = ei + n_edges;

    // 1) copy x into out[:, :48], zero out[:, 48:]
    int init_total = n_nodes * 24;  // float4 count
    int init_blocks = (init_total + 255) / 256;
    init_out_kernel<<<init_blocks, 256, 0, stream>>>(
        (const float4*)x, (float4*)out, n_nodes);

    // 2) edge scatter-add
    long long total = (long long)n_edges * D_IN;
    int blocks = (int)((total + 255) / 256);
    scatter_add_kernel<<<blocks, 256, 0, stream>>>(x, row, col, out, n_edges);
}